// Round 1
// baseline (170.943 us; speedup 1.0000x reference)
//
#include <hip/hip_runtime.h>

#define BN 16
#define AN 3
#define CLS 80
#define GN 52
#define NT 256
#define GG (GN * GN)
#define CH (CLS + 5)     // 85
#define TOTCH (AN * CH)  // 255

__device__ __forceinline__ float sigmoidf_(float v) {
    return 1.0f / (1.0f + expf(-v));
}

// max IoU of pred box (px,py,pw,ph) vs all targets whose batch == fb.
// Must be the EXACT same computation in both kernels (kernel B subtracts
// what kernel A added for the same cell).
__device__ __forceinline__ float max_iou(float px, float py, float pw, float ph, float fb,
                                         const float* s_tb, const float* s_tx,
                                         const float* s_ty, const float* s_tw,
                                         const float* s_th) {
    float px1 = px - pw * 0.5f, px2 = px + pw * 0.5f;
    float py1 = py - ph * 0.5f, py2 = py + ph * 0.5f;
    float pa = pw * ph;
    float m = 0.0f;
    for (int t = 0; t < NT; ++t) {
        if (s_tb[t] == fb) {
            float tw = s_tw[t], th = s_th[t];
            float tx1 = s_tx[t] - tw * 0.5f, tx2 = s_tx[t] + tw * 0.5f;
            float ty1 = s_ty[t] - th * 0.5f, ty2 = s_ty[t] + th * 0.5f;
            float iw = fmaxf(fminf(px2, tx2) - fmaxf(px1, tx1), 0.0f);
            float ih = fmaxf(fminf(py2, ty2) - fmaxf(py1, ty1), 0.0f);
            float inter = iw * ih;
            float uni = pa + tw * th - inter;
            float iou = inter / (uni + 1e-16f);
            m = fmaxf(m, iou);
        }
    }
    return m;
}

__device__ __forceinline__ void block_reduce_add(float local, float* out, int tid) {
    // wave64 shuffle reduce -> 4 partials -> one atomicAdd per block
    for (int off = 32; off > 0; off >>= 1) local += __shfl_down(local, off, 64);
    __shared__ float wsum[4];
    if ((tid & 63) == 0) wsum[tid >> 6] = local;
    __syncthreads();
    if (tid == 0) atomicAdd(out, wsum[0] + wsum[1] + wsum[2] + wsum[3]);
}

// Dense pass: one thread per (b,a,j,i) cell; adds (iou<=0.5 ? sigmoid(conf) : 0)^2
__global__ __launch_bounds__(256) void yolo_dense(const float* __restrict__ x,
                                                  const float* __restrict__ anchors,
                                                  const float* __restrict__ target,
                                                  float* __restrict__ out) {
    __shared__ float s_tb[NT], s_tx[NT], s_ty[NT], s_tw[NT], s_th[NT];
    int tid = threadIdx.x;
    // 256 threads, 256 targets: one each
    s_tb[tid] = target[tid * 7 + 0];
    s_tx[tid] = target[tid * 7 + 2];
    s_ty[tid] = target[tid * 7 + 3];
    s_tw[tid] = target[tid * 7 + 4];
    s_th[tid] = target[tid * 7 + 5];
    __syncthreads();

    int idx = blockIdx.x * 256 + tid;  // grid sized exactly B*A*G*G = 507*256
    int i = idx % GN;
    int j = (idx / GN) % GN;
    int a = (idx / GG) % AN;
    int b = idx / (GG * AN);

    const float* xb = x + ((size_t)(b * TOTCH + a * CH) * GN + j) * GN + i;
    float dx = xb[0];
    float dy = xb[GG];
    float dw = xb[2 * GG];
    float dh = xb[3 * GG];
    float cf = xb[4 * GG];

    float sx = sigmoidf_(dx);
    float sy = sigmoidf_(dy);
    float aw = anchors[a * 2 + 0], ah = anchors[a * 2 + 1];
    float px = (sx + (float)i) / (float)GN;
    float py = (sy + (float)j) / (float)GN;
    float pw = expf(dw) * aw / (float)GN;
    float ph = expf(dh) * ah / (float)GN;

    float miou = max_iou(px, py, pw, ph, (float)b, s_tb, s_tx, s_ty, s_tw, s_th);
    float pc = sigmoidf_(cf);
    float gc = (miou > 0.5f) ? 0.0f : pc;

    block_reduce_add(gc * gc, out, tid);
}

// Sparse pass: one block, one thread per target. Owned valid cells add the
// scattered x/y/w/h/conf/class grad^2 and subtract the dense conf^2 they replace.
__global__ __launch_bounds__(256) void yolo_targets(const float* __restrict__ x,
                                                    const float* __restrict__ anchors,
                                                    const float* __restrict__ target,
                                                    float* __restrict__ out) {
    __shared__ float s_tb[NT], s_tx[NT], s_ty[NT], s_tw[NT], s_th[NT];
    __shared__ int s_cell[NT];
    int t = threadIdx.x;

    float tb = target[t * 7 + 0];
    float tl = target[t * 7 + 1];
    float tx = target[t * 7 + 2];
    float ty = target[t * 7 + 3];
    float tw = target[t * 7 + 4];
    float th = target[t * 7 + 5];
    float ba = target[t * 7 + 6];
    s_tb[t] = tb; s_tx[t] = tx; s_ty[t] = ty; s_tw[t] = tw; s_th[t] = th;

    bool valid = (ba >= 0.0f) && (ba <= 2.0f);
    int b = (int)tb;
    int n = min(max((int)ba, 0), AN - 1);
    float gx = tx * (float)GN, gy = ty * (float)GN;
    int gi = (int)gx, gj = (int)gy;
    s_cell[t] = valid ? (((b * AN + n) * GN + gj) * GN + gi) : -1;
    __syncthreads();

    // dedup: first target in t-order owns a cell (JAX scatter winner is
    // unspecified for dups; collisions are ~0-probability for this seed)
    bool owner = valid;
    if (valid) {
        int mycell = s_cell[t];
        for (int u = 0; u < t; ++u)
            if (s_cell[u] == mycell) { owner = false; break; }
    }

    float contrib = 0.0f;
    if (owner) {
        const float* xb = x + ((size_t)(b * TOTCH + n * CH) * GN + gj) * GN + gi;
        float dx = xb[0];
        float dy = xb[GG];
        float dw = xb[2 * GG];
        float dh = xb[3 * GG];
        float cf = xb[4 * GG];

        float sx = sigmoidf_(dx);
        float sy = sigmoidf_(dy);
        float pc = sigmoidf_(cf);
        float aw = anchors[n * 2 + 0], ah = anchors[n * 2 + 1];
        float scale = 2.0f - tw * th;

        float fx = gx - floorf(gx), fy = gy - floorf(gy);
        float gxv = scale * (sx - fx);
        float gyv = scale * (sy - fy);
        float gwv = scale * (dw - logf(tw * (float)GN / aw + 1e-16f));
        float ghv = scale * (dh - logf(th * (float)GN / ah + 1e-16f));
        contrib = gxv * gxv + gyv * gyv + gwv * gwv + ghv * ghv;

        float gcv = pc - 1.0f;
        contrib += gcv * gcv;

        // subtract what the dense kernel added at this cell (identical recompute)
        float px = (sx + (float)gi) / (float)GN;
        float py = (sy + (float)gj) / (float)GN;
        float pw = expf(dw) * aw / (float)GN;
        float ph = expf(dh) * ah / (float)GN;
        float miou = max_iou(px, py, pw, ph, (float)b, s_tb, s_tx, s_ty, s_tw, s_th);
        float base = (miou > 0.5f) ? 0.0f : pc;
        contrib -= base * base;

        // class grads: sigmoid(prob_c) - onehot(label)
        int label = (int)tl;
        for (int c = 0; c < CLS; ++c) {
            float pp = sigmoidf_(xb[(size_t)(5 + c) * GG]);
            float g = pp - ((c == label) ? 1.0f : 0.0f);
            contrib += g * g;
        }
    }
    block_reduce_add(contrib, out, t);
}

extern "C" void kernel_launch(void* const* d_in, const int* in_sizes, int n_in,
                              void* d_out, int out_size, void* d_ws, size_t ws_size,
                              hipStream_t stream) {
    const float* x = (const float*)d_in[0];
    const float* anchors = (const float*)d_in[1];
    const float* target = (const float*)d_in[2];
    float* out = (float*)d_out;

    hipMemsetAsync(out, 0, sizeof(float), stream);  // d_out is poisoned 0xAA every call

    int cells = BN * AN * GG;  // 129792 = 507 * 256 exactly
    yolo_dense<<<cells / 256, 256, 0, stream>>>(x, anchors, target, out);
    yolo_targets<<<1, 256, 0, stream>>>(x, anchors, target, out);
}

// Round 2
// 89.166 us; speedup vs baseline: 1.9171x; 1.9171x over previous
//
#include <hip/hip_runtime.h>

#define BN 16
#define AN 3
#define CLS 80
#define GN 52
#define NT 256
#define GG (GN * GN)
#define CH (CLS + 5)     // 85
#define EPSF 1e-16f

__device__ __forceinline__ float sigmoidf_(float v) {
    return 1.0f / (1.0f + expf(-v));
}

// "any target in [lo,hi) with IoU > 0.5" — division-free:
// inter/(union+EPS) > 0.5  <=>  inter > 0.5*(union+EPS)   (union+EPS > 0)
__device__ __forceinline__ bool ignore_check(float px, float py, float pw, float ph,
                                             int lo, int hi,
                                             const float* c_x1, const float* c_y1,
                                             const float* c_x2, const float* c_y2,
                                             const float* c_ar) {
    float px1 = px - pw * 0.5f, px2 = px + pw * 0.5f;
    float py1 = py - ph * 0.5f, py2 = py + ph * 0.5f;
    float pa = pw * ph;
    bool ig = false;
    for (int s = lo; s < hi; ++s) {
        float iw = fmaxf(fminf(px2, c_x2[s]) - fmaxf(px1, c_x1[s]), 0.0f);
        float ih = fmaxf(fminf(py2, c_y2[s]) - fmaxf(py1, c_y1[s]), 0.0f);
        float inter = iw * ih;
        float uni = pa + c_ar[s] - inter;
        ig = ig || (inter > 0.5f * (uni + EPSF));
    }
    return ig;
}

__global__ __launch_bounds__(256) void yolo_fused(const float* __restrict__ x,
                                                  const float* __restrict__ anchors,
                                                  const float* __restrict__ target,
                                                  float* __restrict__ out) {
    __shared__ float c_x1[NT], c_y1[NT], c_x2[NT], c_y2[NT], c_ar[NT];
    __shared__ int s_off[BN + 1];
    __shared__ int s_cnt[BN];
    __shared__ int s_cell[NT];
    __shared__ int s_dup;

    int tid = threadIdx.x;

    // ---- Phase A: stage + per-batch compaction of all 256 targets ----
    if (tid < BN) s_cnt[tid] = 0;
    if (tid == 0) s_dup = 0;
    __syncthreads();

    float tb = target[tid * 7 + 0];
    float tx = target[tid * 7 + 2];
    float ty = target[tid * 7 + 3];
    float tw = target[tid * 7 + 4];
    float th = target[tid * 7 + 5];
    float ba = target[tid * 7 + 6];
    int b_t = (int)tb;
    atomicAdd(&s_cnt[b_t], 1);
    __syncthreads();
    if (tid == 0) {
        int acc = 0;
        for (int k = 0; k < BN; ++k) { s_off[k] = acc; acc += s_cnt[k]; }
        s_off[BN] = acc;
    }
    __syncthreads();
    if (tid < BN) s_cnt[tid] = 0;  // reuse as placement cursor
    __syncthreads();
    {
        int slot = s_off[b_t] + atomicAdd(&s_cnt[b_t], 1);
        c_x1[slot] = tx - tw * 0.5f;
        c_x2[slot] = tx + tw * 0.5f;
        c_y1[slot] = ty - th * 0.5f;
        c_y2[slot] = ty + th * 0.5f;
        c_ar[slot] = tw * th;
    }
    // scatter cell id (for dedup/ownership)
    {
        bool valid = (ba >= 0.0f) && (ba <= 2.0f);
        int n = min(max((int)ba, 0), AN - 1);
        int gi = (int)(tx * (float)GN);
        int gj = (int)(ty * (float)GN);
        s_cell[tid] = valid ? (((b_t * AN + n) * GN + gj) * GN + gi) : -1;
    }
    __syncthreads();

    // ---- Phase B: dense conf-grad^2 for this block's 256 cells ----
    int idx = blockIdx.x * 256 + tid;   // grid = 507 blocks exactly
    int i = idx % GN;
    int j = (idx / GN) % GN;
    int a = (idx / GG) % AN;
    int b = idx / (GG * AN);

    const float* xb = x + ((size_t)((b * AN + a) * CH) * GN + j) * GN + i;
    float dx = xb[0];
    float dy = xb[GG];
    float dw = xb[2 * GG];
    float dh = xb[3 * GG];
    float cf = xb[4 * GG];

    float sx = sigmoidf_(dx);
    float sy = sigmoidf_(dy);
    float aw = anchors[a * 2 + 0], ah = anchors[a * 2 + 1];
    float px = (sx + (float)i) / (float)GN;
    float py = (sy + (float)j) / (float)GN;
    float pw = expf(dw) * aw / (float)GN;
    float ph = expf(dh) * ah / (float)GN;

    bool ig = ignore_check(px, py, pw, ph, s_off[b], s_off[b + 1],
                           c_x1, c_y1, c_x2, c_y2, c_ar);
    float pc = sigmoidf_(cf);
    float gc = ig ? 0.0f : pc;
    float local = gc * gc;

    // ---- Phase C: block t (< 256) handles target t, lane-parallel ----
    if (blockIdx.x < NT) {
        int t = blockIdx.x;
        int mycell = s_cell[t];
        // wave-parallel dedup: any earlier target with the same cell?
        if (mycell >= 0 && tid < t && s_cell[tid] == mycell) s_dup = 1;
        __syncthreads();
        bool owner = (mycell >= 0) && (s_dup == 0);
        if (owner) {
            float ttb = target[t * 7 + 0];
            float ttl = target[t * 7 + 1];
            float ttx = target[t * 7 + 2];
            float tty = target[t * 7 + 3];
            float ttw = target[t * 7 + 4];
            float tth = target[t * 7 + 5];
            float tba = target[t * 7 + 6];
            int bb = (int)ttb;
            int n = min(max((int)tba, 0), AN - 1);
            float gx = ttx * (float)GN, gy = tty * (float)GN;
            int gi = (int)gx, gj = (int)gy;
            const float* tp = x + ((size_t)((bb * AN + n) * CH) * GN + gj) * GN + gi;

            if (tid < CLS) {
                // 80 lanes each load one class channel -> parallel latency
                float pp = sigmoidf_(tp[(size_t)(5 + tid) * GG]);
                float g = pp - ((tid == (int)ttl) ? 1.0f : 0.0f);
                local += g * g;
            } else if (tid == CLS) {
                float tdx = tp[0];
                float tdy = tp[GG];
                float tdw = tp[2 * GG];
                float tdh = tp[3 * GG];
                float tcf = tp[4 * GG];
                float tsx = sigmoidf_(tdx);
                float tsy = sigmoidf_(tdy);
                float tpc = sigmoidf_(tcf);
                float naw = anchors[n * 2 + 0], nah = anchors[n * 2 + 1];
                float scale = 2.0f - ttw * tth;
                float fx = gx - floorf(gx), fy = gy - floorf(gy);
                float gxv = scale * (tsx - fx);
                float gyv = scale * (tsy - fy);
                float gwv = scale * (tdw - logf(ttw * (float)GN / naw + EPSF));
                float ghv = scale * (tdh - logf(tth * (float)GN / nah + EPSF));
                float gcv = tpc - 1.0f;
                local += gxv * gxv + gyv * gyv + gwv * gwv + ghv * ghv + gcv * gcv;

                // subtract what phase B added at this cell (bit-identical recompute)
                float tpx = (tsx + (float)gi) / (float)GN;
                float tpy = (tsy + (float)gj) / (float)GN;
                float tpw = expf(tdw) * naw / (float)GN;
                float tph = expf(tdh) * nah / (float)GN;
                bool tig = ignore_check(tpx, tpy, tpw, tph, s_off[bb], s_off[bb + 1],
                                        c_x1, c_y1, c_x2, c_y2, c_ar);
                float base = tig ? 0.0f : tpc;
                local -= base * base;
            }
        }
    }

    // ---- block reduction -> one atomic per block ----
    for (int off = 32; off > 0; off >>= 1) local += __shfl_down(local, off, 64);
    __shared__ float wsum[4];
    if ((tid & 63) == 0) wsum[tid >> 6] = local;
    __syncthreads();
    if (tid == 0) atomicAdd(out, wsum[0] + wsum[1] + wsum[2] + wsum[3]);
}

extern "C" void kernel_launch(void* const* d_in, const int* in_sizes, int n_in,
                              void* d_out, int out_size, void* d_ws, size_t ws_size,
                              hipStream_t stream) {
    const float* x = (const float*)d_in[0];
    const float* anchors = (const float*)d_in[1];
    const float* target = (const float*)d_in[2];
    float* out = (float*)d_out;

    hipMemsetAsync(out, 0, sizeof(float), stream);  // d_out re-poisoned each call

    int blocks = (BN * AN * GG) / 256;  // 507, exact
    yolo_fused<<<blocks, 256, 0, stream>>>(x, anchors, target, out);
}